// Round 5
// baseline (1328.531 us; speedup 1.0000x reference)
//
#include <hip/hip_runtime.h>
#include <cmath>

#define B_  2
#define T_  1024
#define D_  1024
#define H_  16
#define HD_ 64
#define FF_ 4096
#define L_  4
#define M_  128

typedef __bf16 bf16x8 __attribute__((ext_vector_type(8)));
typedef __bf16 bf16x4 __attribute__((ext_vector_type(4)));
typedef float f32x4 __attribute__((ext_vector_type(4)));

__device__ __forceinline__ void async16(const void* g, void* l) {
    __builtin_amdgcn_global_load_lds(
        (const __attribute__((address_space(1))) unsigned int*)g,
        (__attribute__((address_space(3))) unsigned int*)l, 16, 0, 0);
}

// ---------------------------------------------------------------------------
// GEMM: C[M,N] = A[M,K](bf16) @ Wt[N,K](bf16)^T + bias (+res). BK=64.
// LDS rows are 128B (64 bf16) = 8 chunks of 16B; chunk' = chunk ^ (row&7)
// -> ds_read_b128 2-way max (free), global_load_lds lane-linear.
// 4 waves: wm=wave&1 (rows), wn=wave>>1 (cols). Wave tile = BM/2 x BN/2.
// BM=128,BN=64: 16 MFMA/BK-step vs 24KB staged. BM=BN=128: 32 MFMA vs 32KB
// (= the m97-measured 874 TF ratio).
// ---------------------------------------------------------------------------
template<int BM, int BN, typename CT>
__global__ __launch_bounds__(256) void gemm_bf16(
    const __bf16* __restrict__ A, const __bf16* __restrict__ Wt,
    const float* __restrict__ bias, const float* __restrict__ res,
    CT* __restrict__ C, int M, int N, int K)
{
    constexpr int MI = BM / 32;
    constexpr int NI = BN / 32;
    __shared__ alignas(16) __bf16 As[BM * 64];
    __shared__ alignas(16) __bf16 Bs[BN * 64];

    const int tid  = threadIdx.x;
    const int lane = tid & 63;
    const int wave = tid >> 6;
    const int wm   = wave & 1;
    const int wn   = wave >> 1;
    const int quad = lane >> 4;
    const int l16  = lane & 15;
    const int m0   = blockIdx.y * BM;
    const int n0   = blockIdx.x * BN;

    f32x4 acc[MI][NI];
    #pragma unroll
    for (int i = 0; i < MI; i++)
        #pragma unroll
        for (int j = 0; j < NI; j++) acc[i][j] = (f32x4){0.f, 0.f, 0.f, 0.f};

    for (int k0 = 0; k0 < K; k0 += 64) {
        #pragma unroll
        for (int i = 0; i < BM / 32; i++) {
            int off = (i * 256 + tid) * 16;
            int row = off >> 7, chunk = (off >> 4) & 7;
            int gcol = (chunk ^ (row & 7)) * 8;
            async16(A + (size_t)(m0 + row) * K + k0 + gcol,
                    (char*)As + i * 4096 + wave * 1024);
        }
        #pragma unroll
        for (int i = 0; i < BN / 32; i++) {
            int off = (i * 256 + tid) * 16;
            int row = off >> 7, chunk = (off >> 4) & 7;
            int gcol = (chunk ^ (row & 7)) * 8;
            async16(Wt + (size_t)(n0 + row) * K + k0 + gcol,
                    (char*)Bs + i * 4096 + wave * 1024);
        }
        __syncthreads();

        bf16x8 af[MI][2], bfr[NI][2];
        #pragma unroll
        for (int mi = 0; mi < MI; mi++) {
            int r = wm * (BM / 2) + mi * 16 + l16;
            #pragma unroll
            for (int kk = 0; kk < 2; kk++) {
                int c = kk * 4 + quad;
                af[mi][kk] = *(const bf16x8*)((const char*)As + r * 128 + ((c ^ (r & 7)) * 16));
            }
        }
        #pragma unroll
        for (int ni = 0; ni < NI; ni++) {
            int r = wn * (BN / 2) + ni * 16 + l16;
            #pragma unroll
            for (int kk = 0; kk < 2; kk++) {
                int c = kk * 4 + quad;
                bfr[ni][kk] = *(const bf16x8*)((const char*)Bs + r * 128 + ((c ^ (r & 7)) * 16));
            }
        }
        #pragma unroll
        for (int kk = 0; kk < 2; kk++)
            #pragma unroll
            for (int mi = 0; mi < MI; mi++)
                #pragma unroll
                for (int ni = 0; ni < NI; ni++)
                    acc[mi][ni] = __builtin_amdgcn_mfma_f32_16x16x32_bf16(
                        af[mi][kk], bfr[ni][kk], acc[mi][ni], 0, 0, 0);
        __syncthreads();
    }

    #pragma unroll
    for (int mi = 0; mi < MI; mi++) {
        #pragma unroll
        for (int ni = 0; ni < NI; ni++) {
            int col = n0 + wn * (BN / 2) + ni * 16 + l16;
            #pragma unroll
            for (int r = 0; r < 4; r++) {
                int row = m0 + wm * (BM / 2) + mi * 16 + quad * 4 + r;
                float v = acc[mi][ni][r] + bias[col];
                if (res) v += res[(size_t)row * N + col];
                C[(size_t)row * N + col] = (CT)v;
            }
        }
    }
}

// ---------------------------------------------------------------------------
// Fused fc1 + GLU. BM=128, BN=64: block computes cols [n0,n0+64) of 'a' AND
// 'gate' (at FF+n0), writes cc = a * gelu_exact(gate) bf16.
// 32 MFMA per BK=64 step vs 32KB staged (m97 ratio). grid (FF/64, M/128).
// ---------------------------------------------------------------------------
__global__ __launch_bounds__(256) void fc1_glu_kernel(
    const __bf16* __restrict__ A, const __bf16* __restrict__ Wt,
    const float* __restrict__ bias, __bf16* __restrict__ cc, int K)
{
    __shared__ alignas(16) __bf16 As[128 * 64];
    __shared__ alignas(16) __bf16 Bs[64 * 64];
    __shared__ alignas(16) __bf16 Gs[64 * 64];

    const int tid  = threadIdx.x;
    const int lane = tid & 63;
    const int wave = tid >> 6;
    const int wm   = wave & 1;
    const int wn   = wave >> 1;
    const int quad = lane >> 4;
    const int l16  = lane & 15;
    const int m0   = blockIdx.y * 128;
    const int n0   = blockIdx.x * 64;

    f32x4 acc_a[4][2], acc_g[4][2];
    #pragma unroll
    for (int i = 0; i < 4; i++)
        #pragma unroll
        for (int j = 0; j < 2; j++) {
            acc_a[i][j] = (f32x4){0.f, 0.f, 0.f, 0.f};
            acc_g[i][j] = (f32x4){0.f, 0.f, 0.f, 0.f};
        }

    for (int k0 = 0; k0 < K; k0 += 64) {
        #pragma unroll
        for (int i = 0; i < 4; i++) {
            int off = (i * 256 + tid) * 16;
            int row = off >> 7, chunk = (off >> 4) & 7;
            int gcol = (chunk ^ (row & 7)) * 8;
            async16(A + (size_t)(m0 + row) * K + k0 + gcol,
                    (char*)As + i * 4096 + wave * 1024);
        }
        #pragma unroll
        for (int i = 0; i < 2; i++) {
            int off = (i * 256 + tid) * 16;
            int row = off >> 7, chunk = (off >> 4) & 7;
            int gcol = (chunk ^ (row & 7)) * 8;
            async16(Wt + (size_t)(n0 + row) * K + k0 + gcol,
                    (char*)Bs + i * 4096 + wave * 1024);
            async16(Wt + (size_t)(FF_ + n0 + row) * K + k0 + gcol,
                    (char*)Gs + i * 4096 + wave * 1024);
        }
        __syncthreads();

        bf16x8 af[4][2];
        #pragma unroll
        for (int mi = 0; mi < 4; mi++) {
            int r = wm * 64 + mi * 16 + l16;
            #pragma unroll
            for (int kk = 0; kk < 2; kk++) {
                int c = kk * 4 + quad;
                af[mi][kk] = *(const bf16x8*)((const char*)As + r * 128 + ((c ^ (r & 7)) * 16));
            }
        }
        #pragma unroll
        for (int kk = 0; kk < 2; kk++) {
            #pragma unroll
            for (int ni = 0; ni < 2; ni++) {
                int r = wn * 32 + ni * 16 + l16;
                int c = kk * 4 + quad;
                bf16x8 b1 = *(const bf16x8*)((const char*)Bs + r * 128 + ((c ^ (r & 7)) * 16));
                bf16x8 b2 = *(const bf16x8*)((const char*)Gs + r * 128 + ((c ^ (r & 7)) * 16));
                #pragma unroll
                for (int mi = 0; mi < 4; mi++) {
                    acc_a[mi][ni] = __builtin_amdgcn_mfma_f32_16x16x32_bf16(
                        af[mi][kk], b1, acc_a[mi][ni], 0, 0, 0);
                    acc_g[mi][ni] = __builtin_amdgcn_mfma_f32_16x16x32_bf16(
                        af[mi][kk], b2, acc_g[mi][ni], 0, 0, 0);
                }
            }
        }
        __syncthreads();
    }

    #pragma unroll
    for (int mi = 0; mi < 4; mi++) {
        #pragma unroll
        for (int ni = 0; ni < 2; ni++) {
            int col = n0 + wn * 32 + ni * 16 + l16;
            float ba = bias[col], bg = bias[FF_ + col];
            #pragma unroll
            for (int r = 0; r < 4; r++) {
                int row = m0 + wm * 64 + mi * 16 + quad * 4 + r;
                float a = acc_a[mi][ni][r] + ba;
                float g = acc_g[mi][ni][r] + bg;
                float ge = 0.5f * g * (1.0f + erff(g * 0.7071067811865475f));
                cc[(size_t)row * FF_ + col] = (__bf16)(a * ge);
            }
        }
    }
}

// ---------------------------------------------------------------------------
// Weight transpose + cast: W[K,N] f32 -> Wt[N,K] bf16. 64x64 tiles.
// blockIdx.z = layer: src stride K*N, dst stride dstride.
// ---------------------------------------------------------------------------
__global__ __launch_bounds__(256) void transpose_w_kernel(
    const float* __restrict__ W, __bf16* __restrict__ Wt, int K, int N,
    size_t dstride)
{
    W  += (size_t)blockIdx.z * K * N;
    Wt += (size_t)blockIdx.z * dstride;
    __shared__ __bf16 t[64][80];
    int n0 = blockIdx.x * 64, k0 = blockIdx.y * 64;
    int tid = threadIdx.x;
    int r = tid >> 2, cb = (tid & 3) * 16;
    const float* src = W + (size_t)(k0 + r) * N + n0 + cb;
    #pragma unroll
    for (int j = 0; j < 16; j += 4) {
        f32x4 v = *(const f32x4*)(src + j);
        #pragma unroll
        for (int u = 0; u < 4; u++) t[cb + j + u][r] = (__bf16)v[u];
    }
    __syncthreads();
    __bf16* dst = Wt + (size_t)(n0 + r) * K + k0 + cb;
    *(bf16x8*)(dst)     = *(const bf16x8*)&t[r][cb];
    *(bf16x8*)(dst + 8) = *(const bf16x8*)&t[r][cb + 8];
}

// ---------------------------------------------------------------------------
__global__ __launch_bounds__(256) void cvt_bf16_kernel(
    const float* __restrict__ in, __bf16* __restrict__ out)
{
    size_t i = ((size_t)blockIdx.x * 256 + threadIdx.x) * 8;
    f32x4 a = *(const f32x4*)(in + i);
    f32x4 b = *(const f32x4*)(in + i + 4);
    bf16x8 o;
    #pragma unroll
    for (int u = 0; u < 4; u++) { o[u] = (__bf16)a[u]; o[4 + u] = (__bf16)b[u]; }
    *(bf16x8*)(out + i) = o;
}

// ---------------------------------------------------------------------------
template<typename OT>
__global__ __launch_bounds__(256) void ln_kernel(
    const float* __restrict__ in,
    const float* __restrict__ g, const float* __restrict__ b,
    OT* __restrict__ out)
{
    int row = blockIdx.x;
    int t = threadIdx.x;
    __shared__ float red[256];
    __shared__ float red2[256];
    const float* ip = in + (size_t)row * D_;
    float v[4];
    float sum = 0.f, sumsq = 0.f;
    #pragma unroll
    for (int j = 0; j < 4; j++) {
        int c = t + j * 256;
        float x = ip[c];
        v[j] = x;
        sum += x; sumsq += x * x;
    }
    red[t] = sum; red2[t] = sumsq;
    __syncthreads();
    for (int s = 128; s > 0; s >>= 1) {
        if (t < s) { red[t] += red[t + s]; red2[t] += red2[t + s]; }
        __syncthreads();
    }
    float mean = red[0] * (1.0f / D_);
    float var  = red2[0] * (1.0f / D_) - mean * mean;
    float rstd = rsqrtf(var + 1e-5f);
    #pragma unroll
    for (int j = 0; j < 4; j++) {
        int c = t + j * 256;
        out[(size_t)row * D_ + c] = (OT)((v[j] - mean) * rstd * g[c] + b[c]);
    }
}

// ---------------------------------------------------------------------------
// Repack: qkv[B,T,3,H,HD] bf16 -> q,k [BH][T][HD] (roped), v [BH][HD][T].
// grid (T/64, B*H), 256 threads.
// ---------------------------------------------------------------------------
__global__ __launch_bounds__(256) void repack_kernel(
    const __bf16* __restrict__ qkv, __bf16* __restrict__ qp,
    __bf16* __restrict__ kp, __bf16* __restrict__ vp)
{
    int bh = blockIdx.y; int h = bh & (H_ - 1); int b = bh >> 4;
    int t0 = blockIdx.x * 64;
    int tid = threadIdx.x;
    __shared__ __bf16 vt[64][72];

    int r  = tid >> 2;
    int tg = t0 + r;
    int cb = (tid & 3) * 16;       // element base within HD (8 pairs)

    const __bf16* qsrc = qkv + ((size_t)(b * T_ + tg) * 3 + 0) * D_ + h * HD_ + cb;
    const __bf16* ksrc = qkv + ((size_t)(b * T_ + tg) * 3 + 1) * D_ + h * HD_ + cb;
    bf16x8 q0 = *(const bf16x8*)qsrc,  q1 = *(const bf16x8*)(qsrc + 8);
    bf16x8 k0 = *(const bf16x8*)ksrc,  k1 = *(const bf16x8*)(ksrc + 8);
    bf16x8 qo0, qo1, ko0, ko1;
    #pragma unroll
    for (int p = 0; p < 8; p++) {
        int pg = (cb >> 1) + p;               // global pair index 0..31
        int jj = (2 * pg) & 31;
        float f = expf(-(float)jj * (9.210340371976184f / 32.0f));
        float ang = (float)tg * f;
        float c = cosf(ang), s = sinf(ang);
        float qe, qo, ke, ko;
        if (p < 4) { qe = (float)q0[2*p]; qo = (float)q0[2*p+1]; ke = (float)k0[2*p]; ko = (float)k0[2*p+1]; }
        else       { qe = (float)q1[2*(p-4)]; qo = (float)q1[2*(p-4)+1]; ke = (float)k1[2*(p-4)]; ko = (float)k1[2*(p-4)+1]; }
        float a0 = qe * c - qo * s, a1 = qe * s + qo * c;
        float b0 = ke * c - ko * s, b1 = ke * s + ko * c;
        if (p < 4) { qo0[2*p] = (__bf16)a0; qo0[2*p+1] = (__bf16)a1; ko0[2*p] = (__bf16)b0; ko0[2*p+1] = (__bf16)b1; }
        else       { qo1[2*(p-4)] = (__bf16)a0; qo1[2*(p-4)+1] = (__bf16)a1; ko1[2*(p-4)] = (__bf16)b0; ko1[2*(p-4)+1] = (__bf16)b1; }
    }
    size_t odst = ((size_t)bh * T_ + tg) * HD_ + cb;
    *(bf16x8*)(qp + odst) = qo0; *(bf16x8*)(qp + odst + 8) = qo1;
    *(bf16x8*)(kp + odst) = ko0; *(bf16x8*)(kp + odst + 8) = ko1;

    // v transpose
    {
        const __bf16* vsrc = qkv + ((size_t)(b * T_ + tg) * 3 + 2) * D_ + h * HD_ + cb;
        bf16x8 v0 = *(const bf16x8*)vsrc, v1 = *(const bf16x8*)(vsrc + 8);
        #pragma unroll
        for (int u = 0; u < 8; u++) { vt[cb + u][r] = v0[u]; vt[cb + 8 + u][r] = v1[u]; }
    }
    __syncthreads();
    {
        int d = tid >> 2, cb2 = (tid & 3) * 16;
        bf16x8 o0, o1;
        #pragma unroll
        for (int u = 0; u < 8; u++) { o0[u] = vt[d][cb2 + u]; o1[u] = vt[d][cb2 + 8 + u]; }
        __bf16* dst = vp + ((size_t)bh * HD_ + d) * T_ + t0 + cb2;
        *(bf16x8*)(dst) = o0;
        *(bf16x8*)(dst + 8) = o1;
    }
}

// ---------------------------------------------------------------------------
// Flash MFMA attention (unchanged — verified working).
// ---------------------------------------------------------------------------
__global__ __launch_bounds__(256) void attn_mfma_kernel(
    const __bf16* __restrict__ qp, const __bf16* __restrict__ kp,
    const __bf16* __restrict__ vp, const float* __restrict__ rb,
    __bf16* __restrict__ out)
{
    int bh = blockIdx.y; int h = bh & (H_ - 1); int b = bh >> 4;
    int q0 = blockIdx.x * 64;
    int tid = threadIdx.x;
    int lane = tid & 63, wave = tid >> 6;
    int quad = lane >> 4, l16 = lane & 15;

    __shared__ alignas(16) __bf16 Qs[64 * 64];
    __shared__ alignas(16) __bf16 Ks[64 * 64];
    __shared__ alignas(16) __bf16 Vs[64 * 64];
    __shared__ __bf16 Ps[4][16][72];
    __shared__ float rbs[2 * M_ + 1];

    for (int i = tid; i < 2 * M_ + 1; i += 256) rbs[i] = rb[i * H_ + h];

    #pragma unroll
    for (int i = 0; i < 2; i++) {
        int off = (i * 256 + tid) * 16;
        int row = off >> 7, chunk = (off >> 4) & 7;
        int gcol = (chunk ^ (row & 7)) * 8;
        async16(qp + ((size_t)bh * T_ + q0 + row) * HD_ + gcol,
                (char*)Qs + i * 4096 + wave * 1024);
    }
    __syncthreads();

    bf16x8 qfrag[2];
    {
        int r = wave * 16 + l16;
        qfrag[0] = *(const bf16x8*)((const char*)Qs + r * 128 + ((quad)     ^ (r & 7)) * 16);
        qfrag[1] = *(const bf16x8*)((const char*)Qs + r * 128 + ((4 + quad) ^ (r & 7)) * 16);
    }

    float m_run[4], l_run[4];
    f32x4 o_acc[4];
    #pragma unroll
    for (int r2 = 0; r2 < 4; r2++) { m_run[r2] = -1e30f; l_run[r2] = 0.f; }
    #pragma unroll
    for (int ni = 0; ni < 4; ni++) o_acc[ni] = (f32x4){0.f, 0.f, 0.f, 0.f};

    const int row_l  = quad * 4;
    const int qrow_g = q0 + wave * 16 + row_l;

    for (int k0 = 0; k0 < T_; k0 += 64) {
        __syncthreads();
        #pragma unroll
        for (int i = 0; i < 2; i++) {
            int off = (i * 256 + tid) * 16;
            int row = off >> 7, chunk = (off >> 4) & 7;
            int gcol = (chunk ^ (row & 7)) * 8;
            async16(kp + ((size_t)bh * T_ + k0 + row) * HD_ + gcol,
                    (char*)Ks + i * 4096 + wave * 1024);
            async16(vp + ((size_t)bh * HD_ + row) * T_ + k0 + gcol,
                    (char*)Vs + i * 4096 + wave * 1024);
        }
        __syncthreads();

        f32x4 s_acc[4];
        #pragma unroll
        for (int ni = 0; ni < 4; ni++) s_acc[ni] = (f32x4){0.f, 0.f, 0.f, 0.f};
        #pragma unroll
        for (int ni = 0; ni < 4; ni++) {
            int r = ni * 16 + l16;
            bf16x8 kf0 = *(const bf16x8*)((const char*)Ks + r * 128 + ((quad)     ^ (r & 7)) * 16);
            bf16x8 kf1 = *(const bf16x8*)((const char*)Ks + r * 128 + ((4 + quad) ^ (r & 7)) * 16);
            s_acc[ni] = __builtin_amdgcn_mfma_f32_16x16x32_bf16(qfrag[0], kf0, s_acc[ni], 0, 0, 0);
            s_acc[ni] = __builtin_amdgcn_mfma_f32_16x16x32_bf16(qfrag[1], kf1, s_acc[ni], 0, 0, 0);
        }

        float sv[4][4];
        float rmax[4] = {-1e30f, -1e30f, -1e30f, -1e30f};
        #pragma unroll
        for (int ni = 0; ni < 4; ni++) {
            int colg = k0 + ni * 16 + l16;
            #pragma unroll
            for (int r2 = 0; r2 < 4; r2++) {
                int rel = colg - (qrow_g + r2);
                rel = (rel < -M_) ? -M_ : (rel > M_ ? M_ : rel);
                float s = s_acc[ni][r2] * 0.125f + rbs[rel + M_];
                sv[ni][r2] = s;
                rmax[r2] = fmaxf(rmax[r2], s);
            }
        }
        #pragma unroll
        for (int r2 = 0; r2 < 4; r2++)
            #pragma unroll
            for (int off = 1; off < 16; off <<= 1)
                rmax[r2] = fmaxf(rmax[r2], __shfl_xor(rmax[r2], off, 64));

        float alpha[4], rsum[4];
        #pragma unroll
        for (int r2 = 0; r2 < 4; r2++) {
            float mn = fmaxf(m_run[r2], rmax[r2]);
            alpha[r2] = __expf(m_run[r2] - mn);
            m_run[r2] = mn;
            rsum[r2] = 0.f;
        }
        #pragma unroll
        for (int ni = 0; ni < 4; ni++)
            #pragma unroll
            for (int r2 = 0; r2 < 4; r2++) {
                float p = __expf(sv[ni][r2] - m_run[r2]);
                rsum[r2] += p;
                Ps[wave][row_l + r2][ni * 16 + l16] = (__bf16)p;
            }
        #pragma unroll
        for (int r2 = 0; r2 < 4; r2++) {
            #pragma unroll
            for (int off = 1; off < 16; off <<= 1)
                rsum[r2] += __shfl_xor(rsum[r2], off, 64);
            l_run[r2] = l_run[r2] * alpha[r2] + rsum[r2];
        }
        #pragma unroll
        for (int ni = 0; ni < 4; ni++)
            #pragma unroll
            for (int r2 = 0; r2 < 4; r2++) o_acc[ni][r2] *= alpha[r2];

        #pragma unroll
        for (int kk = 0; kk < 2; kk++) {
            bf16x8 pfrag = *(const bf16x8*)&Ps[wave][l16][kk * 32 + quad * 8];
            #pragma unroll
            for (int ni = 0; ni < 4; ni++) {
                int r = ni * 16 + l16;
                bf16x8 vfrag = *(const bf16x8*)((const char*)Vs + r * 128 + ((kk * 4 + quad) ^ (r & 7)) * 16);
                o_acc[ni] = __builtin_amdgcn_mfma_f32_16x16x32_bf16(pfrag, vfrag, o_acc[ni], 0, 0, 0);
            }
        }
    }

    #pragma unroll
    for (int ni = 0; ni < 4; ni++) {
        int colg = h * HD_ + ni * 16 + l16;
        #pragma unroll
        for (int r2 = 0; r2 < 4; r2++) {
            int rowg = qrow_g + r2;
            out[(size_t)(b * T_ + rowg) * D_ + colg] = (__bf16)(o_acc[ni][r2] / l_run[r2]);
        }
    }
}

// ---------------------------------------------------------------------------
__global__ __launch_bounds__(256) void final_kernel(
    const float* __restrict__ o, const float* __restrict__ alpha,
    const float* __restrict__ beta, const float* __restrict__ alpha_scale,
    const float* __restrict__ beta_scale, float* __restrict__ outp)
{
    int row = blockIdx.x;
    int t = threadIdx.x;
    __shared__ float red[256];
    const float* op = o + (size_t)row * D_;
    float v[4];
    float sumsq = 0.f;
    #pragma unroll
    for (int j = 0; j < 4; j++) {
        float x = op[t + j * 256];
        v[j] = x;
        sumsq += x * x;
    }
    red[t] = sumsq; __syncthreads();
    for (int s = 128; s > 0; s >>= 1) {
        if (t < s) red[t] += red[t + s];
        __syncthreads();
    }
    float ms = sqrtf(red[0]);
    float as = fminf(fmaxf(alpha_scale[0], 0.f), 1.f);
    float sc = 1.0f + alpha[0] * as * fminf(ms, 5.0f);
    float bb = beta[0] * beta_scale[0];
    #pragma unroll
    for (int j = 0; j < 4; j++) {
        float x = v[j] * sc + bb;
        x = fminf(fmaxf(x, -10.f), 10.f);
        outp[(size_t)row * D_ + t + j * 256] = x + v[j];
    }
}

// ---------------------------------------------------------------------------
extern "C" void kernel_launch(void* const* d_in, const int* in_sizes, int n_in,
                              void* d_out, int out_size, void* d_ws, size_t ws_size,
                              hipStream_t stream)
{
    const float* x        = (const float*)d_in[0];
    const float* context  = (const float*)d_in[1];
    const float* W_in     = (const float*)d_in[2];
    const float* b_in     = (const float*)d_in[3];
    const float* ln_in_g  = (const float*)d_in[4];
    const float* ln_in_b  = (const float*)d_in[5];
    const float* ln1_g    = (const float*)d_in[6];
    const float* ln1_b    = (const float*)d_in[7];
    const float* Wqkv     = (const float*)d_in[8];
    const float* bqkv     = (const float*)d_in[9];
    const float* Wproj    = (const float*)d_in[10];
    const float* bproj    = (const float*)d_in[11];
    const float* rel_bias = (const float*)d_in[12];
    const float* ln2_g    = (const float*)d_in[13];
    const float* ln2_b    = (const float*)d_in[14];
    const float* Wfc1     = (const float*)d_in[15];
    const float* bfc1     = (const float*)d_in[16];
    const float* Wfc2     = (const float*)d_in[17];
    const float* bfc2     = (const float*)d_in[18];
    const float* ln_f_g   = (const float*)d_in[19];
    const float* ln_f_b   = (const float*)d_in[20];
    const float* W_out    = (const float*)d_in[21];
    const float* b_out    = (const float*)d_in[22];
    const float* alpha    = (const float*)d_in[23];
    const float* beta     = (const float*)d_in[24];
    const float* alpha_s  = (const float*)d_in[25];
    const float* beta_s   = (const float*)d_in[26];

    float* ws = (float*)d_ws;
    const size_t MLN = 1024 * 1024;
    const int MROWS = B_ * T_;                            // 2048

    float*  h    = ws;                                    // [0, 2M) f32
    __bf16* hnb  = (__bf16*)(ws + 2 * MLN);               // 2M bf16
    __bf16* abuf = (__bf16*)(ws + 3 * MLN);               // 2M bf16 (x_bf / attnout)
    __bf16* qpk  = (__bf16*)(ws + 4 * MLN);
    __bf16* kpk  = (__bf16*)(ws + 5 * MLN);
    __bf16* vpk  = (__bf16*)(ws + 6 * MLN);
    __bf16* qkvb = (__bf16*)(ws + 8 * MLN);               // 6.29M bf16
    __bf16* ccb  = (__bf16*)(ws + 12 * MLN);              // 8.39M bf16
    float*  tmpf = ws + 17 * MLN;                         // 2M f32 (in/out proj out)
    __bf16* wtb  = (__bf16*)(ws + 19 * MLN);              // transposed weights

    __bf16* wt_in  = wtb;
    __bf16* wt_out = wtb + 1048576;
    const size_t LSTRIDE = 16777216;
    __bf16* wt_qkv0  = wtb + 2097152;
    __bf16* wt_proj0 = wt_qkv0 + 3145728;
    __bf16* wt_fc10  = wt_qkv0 + 4194304;
    __bf16* wt_fc20  = wt_qkv0 + 12582912;

    dim3 blk(256);

    // --- all weight transposes up front ---
    transpose_w_kernel<<<dim3(16, 16, 1),  blk, 0, stream>>>(W_in,  wt_in,  D_, D_, 0);
    transpose_w_kernel<<<dim3(16, 16, 1),  blk, 0, stream>>>(W_out, wt_out, D_, D_, 0);
    transpose_w_kernel<<<dim3(48, 16, 4),  blk, 0, stream>>>(Wqkv,  wt_qkv0,  D_, 3 * D_, LSTRIDE);
    transpose_w_kernel<<<dim3(16, 16, 4),  blk, 0, stream>>>(Wproj, wt_proj0, D_, D_, LSTRIDE);
    transpose_w_kernel<<<dim3(128, 16, 4), blk, 0, stream>>>(Wfc1,  wt_fc10,  D_, 2 * FF_, LSTRIDE);
    transpose_w_kernel<<<dim3(16, 64, 4),  blk, 0, stream>>>(Wfc2,  wt_fc20,  FF_, D_, LSTRIDE);

    // --- input projection + LN ---
    cvt_bf16_kernel<<<dim3(1024), blk, 0, stream>>>(x, abuf);
    gemm_bf16<128, 64, float><<<dim3(16, 16), blk, 0, stream>>>(abuf, wt_in, b_in, context,
                                                                tmpf, MROWS, D_, D_);
    ln_kernel<float><<<dim3(MROWS), blk, 0, stream>>>(tmpf, ln_in_g, ln_in_b, h);

    for (int l = 0; l < L_; l++) {
        const float* bq   = bqkv + (size_t)l * 3 * D_;
        const float* bp   = bproj + (size_t)l * D_;
        const float* rb   = rel_bias + (size_t)l * (2 * M_ + 1) * H_;
        const float* bf1  = bfc1 + (size_t)l * 2 * FF_;
        const float* bf2  = bfc2 + (size_t)l * D_;
        __bf16* wt_qkv  = wt_qkv0  + (size_t)l * LSTRIDE;
        __bf16* wt_proj = wt_proj0 + (size_t)l * LSTRIDE;
        __bf16* wt_fc1  = wt_fc10  + (size_t)l * LSTRIDE;
        __bf16* wt_fc2  = wt_fc20  + (size_t)l * LSTRIDE;

        ln_kernel<__bf16><<<dim3(MROWS), blk, 0, stream>>>(h, ln1_g + l * D_, ln1_b + l * D_, hnb);
        gemm_bf16<128, 128, __bf16><<<dim3(24, 16), blk, 0, stream>>>(hnb, wt_qkv, bq, nullptr,
                                                                      qkvb, MROWS, 3 * D_, D_);
        repack_kernel<<<dim3(T_ / 64, B_ * H_), blk, 0, stream>>>(qkvb, qpk, kpk, vpk);
        attn_mfma_kernel<<<dim3(T_ / 64, B_ * H_), blk, 0, stream>>>(qpk, kpk, vpk, rb, abuf);
        gemm_bf16<128, 64, float><<<dim3(16, 16), blk, 0, stream>>>(abuf, wt_proj, bp, h, h,
                                                                    MROWS, D_, D_);
        ln_kernel<__bf16><<<dim3(MROWS), blk, 0, stream>>>(h, ln2_g + l * D_, ln2_b + l * D_, hnb);
        fc1_glu_kernel<<<dim3(64, 16), blk, 0, stream>>>(hnb, wt_fc1, bf1, ccb, D_);
        gemm_bf16<128, 64, float><<<dim3(16, 16), blk, 0, stream>>>(ccb, wt_fc2, bf2, h, h,
                                                                    MROWS, D_, FF_);
    }

    ln_kernel<__bf16><<<dim3(MROWS), blk, 0, stream>>>(h, ln_f_g, ln_f_b, hnb);
    gemm_bf16<128, 64, float><<<dim3(16, 16), blk, 0, stream>>>(hnb, wt_out, b_out, nullptr,
                                                                tmpf, MROWS, D_, D_);
    final_kernel<<<dim3(MROWS), blk, 0, stream>>>(tmpf, alpha, beta, alpha_s, beta_s,
                                                  (float*)d_out);
}